// Round 10
// baseline (545.986 us; speedup 1.0000x reference)
//
#include <hip/hip_runtime.h>

// Problem constants
constexpr int B    = 32;
constexpr int CIN  = 64;
constexpr int COUT = 128;
constexpr int T    = 300;
constexpr int V    = 25;
constexpr int TV   = T * V;            // 7500
constexpr long long NPC   = (long long)B * TV;          // 240000 per channel
constexpr long long TOTAL = (long long)B * COUT * TV;   // 30,720,000

typedef short          bf16x8 __attribute__((ext_vector_type(8)));
typedef float          f32x4  __attribute__((ext_vector_type(4)));
typedef unsigned short us8    __attribute__((ext_vector_type(8)));
typedef unsigned short us4    __attribute__((ext_vector_type(4)));

static __device__ __forceinline__ unsigned short f2bf(float f) {
  union { float f; unsigned u; } x; x.f = f;
  unsigned r = x.u + 0x7FFFu + ((x.u >> 16) & 1u);   // RNE
  return (unsigned short)(r >> 16);
}
static __device__ __forceinline__ float bf2f(unsigned short u) {
  union { unsigned u; float f; } x; x.u = ((unsigned)u) << 16;
  return x.f;
}

// swizzled offsets for kA5 LDS tiles (verified rounds 4-9)
static __device__ __forceinline__ int xoff(int pos, int c) {      // [pos][c<64]
  return pos * 64 + ((((c >> 3)) ^ (pos & 7)) << 3) + (c & 7);
}
static __device__ __forceinline__ int soff(int c, int pw) {       // [c][pw<128]
  return c * 128 + ((((pw >> 3)) ^ (c & 7)) << 3) + (pw & 7);
}

// ---------------------------------------------------------------------------
// kPrep: all weight/graph-matrix prep in one launch. 696 blocks x 256.
// ---------------------------------------------------------------------------
__global__ __launch_bounds__(256) void kPrep(
    const float* __restrict__ w_t, const float* __restrict__ w_r,
    const float* __restrict__ w_sp, const float* __restrict__ A_hat,
    unsigned short* __restrict__ wb2, unsigned short* __restrict__ wrs2,
    unsigned short* __restrict__ bdt)
{
  int i = blockIdx.x * 256 + threadIdx.x;
  if (i < 147456) {
    int c = i & 127, ok = i >> 7;
    int k = ok % 9, o = ok / 9;
    int idx = ((k * 16 + (c >> 3)) * 128 + o) * 8 + (c & 7);
    wb2[idx] = f2bf(w_t[(o * COUT + c) * 9 + k]);
  } else if (i < 147456 + 16384) {
    int j = i - 147456;
    int c = j & 63, row = j >> 6;
    float v = (row < COUT) ? w_r[row * CIN + c] : w_sp[(row - COUT) * CIN + c];
    wrs2[((c >> 3) * 256 + row) * 8 + (c & 7)] = f2bf(v);
  } else {
    int j = i - 147456 - 16384;
    int pv = j >> 7, pw = j & 127;
    float v = 0.f;
    if (pv < 100 && pw < 100 && (pv / 25) == (pw / 25))
      v = A_hat[(pv % 25) * 25 + (pw % 25)];
    bdt[j] = f2bf(v);
  }
}

// ---------------------------------------------------------------------------
// kA5: all-MFMA spatial front-end + fused BN-stats partials.
// Changes vs r9 kA4: axsp aliases xs (LDS 30.7KB -> 5 blocks/CU); BOTH
// outputs in [b][pos][c] us4-packed layout; transpose-butterfly stats.
// grid (75, 32), 4 waves.
// ---------------------------------------------------------------------------
__global__ __launch_bounds__(256, 5) void kA5(
    const float* __restrict__ x, const unsigned short* __restrict__ bdt,
    const unsigned short* __restrict__ wrs2,
    unsigned short* __restrict__ resb, unsigned short* __restrict__ h,
    float2* __restrict__ part_rs)
{
  __shared__ unsigned short xs[64 * 128];    // 16KB; reused as axsp after S2
  __shared__ unsigned short xsp[112 * 64];   // 14KB
  unsigned short* axsp = xs;                 // alias: axsp[pv][c] 112x64 < 8192

  const int tid  = threadIdx.x;
  const int lane = tid & 63;
  const int wave = tid >> 6;
  const int b    = blockIdx.y;
  const int p0   = blockIdx.x * 100;
  const int grp  = lane >> 4;
  const int l15  = lane & 15;

  for (int u = tid; u < 16 * 128; u += 256) {
    int pos = u & 127, c4 = u >> 7;
    int c0 = c4 * 4;
    float v0 = 0.f, v1 = 0.f, v2 = 0.f, v3 = 0.f;
    if (pos < 100) {
      const float* xp = &x[(b * CIN + c0) * TV + p0 + pos];
      v0 = xp[0]; v1 = xp[TV]; v2 = xp[2 * TV]; v3 = xp[3 * TV];
    }
    unsigned short b0 = f2bf(v0), b1 = f2bf(v1), b2 = f2bf(v2), b3 = f2bf(v3);
    xs[soff(c0,     pos)] = b0;
    xs[soff(c0 + 1, pos)] = b1;
    xs[soff(c0 + 2, pos)] = b2;
    xs[soff(c0 + 3, pos)] = b3;
    if (pos < 112) {
      us4 pk = {b0, b1, b2, b3};
      *(us4*)&xsp[xoff(pos, c0)] = pk;
    }
  }
  __syncthreads();                       // S1: staging done

  bf16x8 xf[4];
#pragma unroll
  for (int ks = 0; ks < 4; ++ks)
    xf[ks] = *(const bf16x8*)&xs[soff(wave * 16 + l15, ks * 32 + grp * 8)];
  __syncthreads();                       // S2: xf in regs; xs reusable

  // mix GEMM (sparse block-diagonal k-steps, table VERIFIED round 5)
  {
    f32x4 macc[7];
#pragma unroll
    for (int ni = 0; ni < 7; ++ni) macc[ni] = (f32x4)0.f;
    const int kst[7] = {0, 0, 0, 0, 1, 2, 2};
    const int kcn[7] = {1, 2, 2, 3, 3, 2, 2};
#pragma unroll
    for (int ni = 0; ni < 7; ++ni) {
      for (int kk = 0; kk < kcn[ni]; ++kk) {
        int ks = kst[ni] + kk;
        bf16x8 gf = *(const bf16x8*)&bdt[(ni * 16 + l15) * 128 + ks * 32 + grp * 8];
        macc[ni] = __builtin_amdgcn_mfma_f32_16x16x32_bf16(xf[ks], gf, macc[ni], 0, 0, 0);
      }
    }
#pragma unroll
    for (int ni = 0; ni < 7; ++ni) {
#pragma unroll
      for (int r = 0; r < 4; ++r)
        axsp[xoff(ni * 16 + l15, wave * 16 + grp * 4 + r)] = f2bf(macc[ni][r]);
    }
  }
  __syncthreads();                       // S3: axsp ready

  const unsigned short* bsrc = (wave < 2) ? xsp : axsp;
  f32x4 acc[4][7];
#pragma unroll
  for (int m = 0; m < 4; ++m)
#pragma unroll
    for (int n = 0; n < 7; ++n) acc[m][n] = (f32x4)0.f;

#pragma unroll
  for (int ks = 0; ks < 2; ++ks) {
    bf16x8 af[4], bfr[7];
#pragma unroll
    for (int mi = 0; mi < 4; ++mi) {
      int row = wave * 64 + mi * 16 + l15;
      af[mi] = *(const bf16x8*)&wrs2[((ks * 4 + grp) * 256 + row) * 8];
    }
#pragma unroll
    for (int ni = 0; ni < 7; ++ni)
      bfr[ni] = *(const bf16x8*)&bsrc[xoff(ni * 16 + l15, ks * 32 + grp * 8)];
#pragma unroll
    for (int mi = 0; mi < 4; ++mi)
#pragma unroll
      for (int ni = 0; ni < 7; ++ni)
        acc[mi][ni] = __builtin_amdgcn_mfma_f32_16x16x32_bf16(
            af[mi], bfr[ni], acc[mi][ni], 0, 0, 0);
  }

  // epilogue: us4 packs, [b][pos][c] layout for BOTH outputs
  {
    unsigned short* dst = (wave < 2) ? resb : h;
#pragma unroll
    for (int mi = 0; mi < 4; ++mi) {
      const int c0 = (wave & 1) * 64 + mi * 16 + grp * 4;
#pragma unroll
      for (int ni = 0; ni < 7; ++ni) {
        int pos = ni * 16 + l15;
        if (pos < 100) {
          us4 pk;
#pragma unroll
          for (int r = 0; r < 4; ++r) pk[r] = f2bf(acc[mi][ni][r]);
          *(us4*)&dst[((long long)(b * TV + p0 + pos)) * COUT + c0] = pk;
        }
      }
    }
  }

  // fused BN stats: transpose-butterfly (15 pair-steps), all lanes store
  {
    float sv[16], qv[16];
#pragma unroll
    for (int mi = 0; mi < 4; ++mi)
#pragma unroll
      for (int r = 0; r < 4; ++r) {
        float s = 0.f, q = 0.f;
#pragma unroll
        for (int ni = 0; ni < 7; ++ni) {
          float v = (ni < 6 || l15 < 4) ? acc[mi][ni][r] : 0.f;  // pos<100
          s += v; q += v * v;
        }
        sv[mi * 4 + r] = s; qv[mi * 4 + r] = q;
      }
#pragma unroll
    for (int bm = 1; bm < 16; bm <<= 1) {
      const bool up = (l15 & bm) != 0;
#pragma unroll
      for (int i = 0; i < 16; i += 2 * bm) {
        const int j = i + bm;
        float ssend = up ? sv[i] : sv[j];
        float qsend = up ? qv[i] : qv[j];
        float sgot = __shfl_xor(ssend, bm);
        float qgot = __shfl_xor(qsend, bm);
        sv[i] = (up ? sv[j] : sv[i]) + sgot;
        qv[i] = (up ? qv[j] : qv[i]) + qgot;
      }
    }
    // lane l15 holds (s,q) for mi = l15>>2, r = l15&3
    int slot = ((l15 >> 2) * 16) + grp * 4 + (l15 & 3);
    float2* pw = &part_rs[(((long long)(blockIdx.y * 75 + blockIdx.x)) * 4 + wave) * 64];
    pw[slot] = make_float2(sv[0], qv[0]);
  }
}

// ---------------------------------------------------------------------------
// kC2v2: finalize res & sp BN from kA5 partials. grid 256. (unchanged)
// scales: [0]=sc_r [128]=sh_r [256]=sc_s [384]=sh_s [512]=sc_t [640]=sh_t
// ---------------------------------------------------------------------------
__global__ __launch_bounds__(256) void kC2v2(
    const float2* __restrict__ part_rs,
    const float* __restrict__ g_r,  const float* __restrict__ be_r,
    const float* __restrict__ g_sp, const float* __restrict__ be_sp,
    float* __restrict__ scales)
{
  __shared__ float rs[256], rq[256];
  const int row = blockIdx.x;
  const int wave = row >> 6, local = row & 63;
  const int tid = threadIdx.x;
  float s = 0.f, q = 0.f;
  for (int bid = tid; bid < 2400; bid += 256) {
    float2 v = part_rs[((long long)bid * 4 + wave) * 64 + local];
    s += v.x; q += v.y;
  }
  rs[tid] = s; rq[tid] = q;
  __syncthreads();
  for (int st = 128; st > 0; st >>= 1) {
    if (tid < st) { rs[tid] += rs[tid + st]; rq[tid] += rq[tid + st]; }
    __syncthreads();
  }
  if (tid == 0) {
    const float n = (float)NPC;
    float m = rs[0] / n, var = rq[0] / n - m * m;
    float iv = rsqrtf(var + 1e-5f);
    if (row < 128) {
      float sc = g_r[row] * iv;
      scales[row] = sc; scales[128 + row] = be_r[row] - m * sc;
    } else {
      int c = row - 128;
      float sc = g_sp[c] * iv;
      scales[256 + c] = sc; scales[384 + c] = be_sp[c] - m * sc;
    }
  }
}

// ---------------------------------------------------------------------------
// kE8: temporal conv 9x1, implicit MFMA GEMM. NP=192 tile, 512 threads /
// 8 waves (2 wm x 4 wn x 48 pos), 50KB LDS -> 3 blocks/CU (24 waves, 75%).
// BN_s+ReLU fused in swizzled staging (0 conflicts); cvb in [b][pos][c]
// us4-packed; transpose-butterfly BN_t stats; setprio. grid (40, 32).
// ---------------------------------------------------------------------------
constexpr int NP    = 192;
constexpr int HALO  = 100;               // 4*25
constexpr int STAGE = NP + 2 * HALO;     // 392

__global__ __launch_bounds__(512, 6) void kE8(
    const unsigned short* __restrict__ h, const unsigned short* __restrict__ wb2,
    const float* __restrict__ scales, unsigned short* __restrict__ cvb,
    float2* __restrict__ part_t)
{
  __shared__ unsigned short hs[STAGE * 64];   // 50176 B
  const int tid  = threadIdx.x;
  const int lane = tid & 63;
  const int wave = tid >> 6;          // 0..7
  const int wm   = wave >> 2, wn = wave & 3;
  const int b    = blockIdx.y;
  const int p0   = blockIdx.x * NP;
  const int grp  = lane >> 4;
  const int l15  = lane & 15;
  const int slot = tid & 7;

  f32x4 acc[4][3];
#pragma unroll
  for (int m = 0; m < 4; ++m)
#pragma unroll
    for (int n = 0; n < 3; ++n) acc[m][n] = (f32x4)0.f;

  for (int cc = 0; cc < 2; ++cc) {
    if (cc) __syncthreads();             // prev chunk's MFMA reads done
    const int c0 = cc * 64;
    float sc[8], sh[8];
#pragma unroll
    for (int e = 0; e < 8; ++e) {
      sc[e] = scales[256 + c0 + slot * 8 + e];
      sh[e] = scales[384 + c0 + slot * 8 + e];
    }
    for (int i = tid; i < STAGE * 8; i += 512) {
      int pos = i >> 3;
      int pg = p0 - HALO + pos;
      us8 o = (us8)(unsigned short)0;
      if (pg >= 0 && pg < TV) {
        us8 v = *(const us8*)&h[((long long)b * TV + pg) * COUT + c0 + slot * 8];
#pragma unroll
        for (int e = 0; e < 8; ++e)
          o[e] = f2bf(fmaxf(bf2f(v[e]) * sc[e] + sh[e], 0.f));
      }
      int si = (pos << 6) + ((slot ^ (pos & 7)) << 3);
      *(us8*)&hs[si] = o;
    }
    __syncthreads();

    __builtin_amdgcn_s_setprio(1);
    for (int k = 0; k < 9; ++k) {
      const int plb = HALO + wn * 48 + 25 * (k - 4) + l15;
#pragma unroll
      for (int ks = 0; ks < 2; ++ks) {
        bf16x8 af[4], bfr[3];
#pragma unroll
        for (int mi = 0; mi < 4; ++mi) {
          int o = wm * 64 + mi * 16 + l15;
          af[mi] = *(const bf16x8*)&wb2[((k * 16 + cc * 8 + ks * 4 + grp) * 128 + o) * 8];
        }
#pragma unroll
        for (int ni = 0; ni < 3; ++ni) {
          int pl = plb + ni * 16;
          int si = (pl << 6) + (((ks * 4 + grp) ^ (pl & 7)) << 3);
          bfr[ni] = *(const bf16x8*)&hs[si];
        }
#pragma unroll
        for (int mi = 0; mi < 4; ++mi)
#pragma unroll
          for (int ni = 0; ni < 3; ++ni)
            acc[mi][ni] = __builtin_amdgcn_mfma_f32_16x16x32_bf16(
                af[mi], bfr[ni], acc[mi][ni], 0, 0, 0);
      }
    }
    __builtin_amdgcn_s_setprio(0);
  }

  // epilogue: conv -> cvb bf16, [b][pos][c] us4-packed
#pragma unroll
  for (int mi = 0; mi < 4; ++mi) {
    const int c0 = wm * 64 + mi * 16 + grp * 4;
#pragma unroll
    for (int ni = 0; ni < 3; ++ni) {
      int pos = p0 + wn * 48 + ni * 16 + l15;
      if (pos < TV) {
        us4 pk;
#pragma unroll
        for (int r = 0; r < 4; ++r) pk[r] = f2bf(acc[mi][ni][r]);
        *(us4*)&cvb[((long long)(b * TV + pos)) * COUT + c0] = pk;
      }
    }
  }

  // fused BN_t stats: transpose-butterfly, [bid][wave(8)][64]
  {
    float sv[16], qv[16];
#pragma unroll
    for (int mi = 0; mi < 4; ++mi)
#pragma unroll
      for (int r = 0; r < 4; ++r) {
        float s = 0.f, q = 0.f;
#pragma unroll
        for (int ni = 0; ni < 3; ++ni) {
          int pos = p0 + wn * 48 + ni * 16 + l15;
          float v = (pos < TV) ? acc[mi][ni][r] : 0.f;
          s += v; q += v * v;
        }
        sv[mi * 4 + r] = s; qv[mi * 4 + r] = q;
      }
#pragma unroll
    for (int bm = 1; bm < 16; bm <<= 1) {
      const bool up = (l15 & bm) != 0;
#pragma unroll
      for (int i = 0; i < 16; i += 2 * bm) {
        const int j = i + bm;
        float ssend = up ? sv[i] : sv[j];
        float qsend = up ? qv[i] : qv[j];
        float sgot = __shfl_xor(ssend, bm);
        float qgot = __shfl_xor(qsend, bm);
        sv[i] = (up ? sv[j] : sv[i]) + sgot;
        qv[i] = (up ? qv[j] : qv[i]) + qgot;
      }
    }
    int slt = ((l15 >> 2) * 16) + grp * 4 + (l15 & 3);
    float2* pw = &part_t[(((long long)(blockIdx.y * 40 + blockIdx.x)) * 8 + wave) * 64];
    pw[slt] = make_float2(sv[0], qv[0]);
  }
}

// ---------------------------------------------------------------------------
// kG2: finalize temporal BN from kE8 partials. grid 128.
// channel c = wm*64 + local; waves wm*4+wn (wn 0..3) of 1280 blocks.
// ---------------------------------------------------------------------------
__global__ __launch_bounds__(256) void kG2(
    const float2* __restrict__ part_t,
    const float* __restrict__ g_t, const float* __restrict__ be_t,
    float* __restrict__ scales)
{
  __shared__ float rs[256], rq[256];
  const int c = blockIdx.x;
  const int wm = c >> 6, local = c & 63;
  const int tid = threadIdx.x;
  const int NB = 40 * 32;              // 1280 blocks
  float s = 0.f, q = 0.f;
  for (int p = tid; p < NB * 4; p += 256) {
    int bid = p >> 2, wn = p & 3;
    float2 v = part_t[((long long)bid * 8 + (wm * 4 + wn)) * 64 + local];
    s += v.x; q += v.y;
  }
  rs[tid] = s; rq[tid] = q;
  __syncthreads();
  for (int st = 128; st > 0; st >>= 1) {
    if (tid < st) { rs[tid] += rs[tid + st]; rq[tid] += rq[tid + st]; }
    __syncthreads();
  }
  if (tid == 0) {
    const float n = (float)NPC;
    float m = rs[0] / n, var = rq[0] / n - m * m;
    float sc = g_t[c] * rsqrtf(var + 1e-5f);
    scales[512 + c] = sc;
    scales[640 + c] = be_t[c] - m * sc;
  }
}

// ---------------------------------------------------------------------------
// kH2: out = relu(cvb*sc_t+sh_t + resb*sc_r+sh_r); inputs [b][pos][c] bf16,
// output NCHW fp32. Unit = 64 lanes: (b, c-slot(16), pos-tile 256). Lane
// reads 4 consecutive rows' us8 slice, writes 8 float4 coalesced stores.
// grid 3840 x 256 (15360 units / 4).
// ---------------------------------------------------------------------------
__global__ __launch_bounds__(256) void kH2(
    const unsigned short* __restrict__ cvb, const unsigned short* __restrict__ resb,
    const float* __restrict__ scales, float* __restrict__ out)
{
  const int tid  = threadIdx.x;
  const int lane = tid & 63;
  const int unit = blockIdx.x * 4 + (tid >> 6);   // ((b*16+slot)*30 + pt)
  const int pt   = unit % 30;
  const int rest = unit / 30;
  const int cslot = rest & 15;
  const int b    = rest >> 4;
  const int c0   = cslot * 8;
  float sct[8], sht[8], scr[8], shr[8];
#pragma unroll
  for (int e = 0; e < 8; ++e) {
    sct[e] = scales[512 + c0 + e]; sht[e] = scales[640 + c0 + e];
    scr[e] = scales[c0 + e];       shr[e] = scales[128 + c0 + e];
  }
  const int pbase = pt * 256 + lane * 4;
  if (pbase + 4 > TV) return;        // tail tile: lanes >= 19 idle
  float y[4][8];
#pragma unroll
  for (int j = 0; j < 4; ++j) {
    long long row = ((long long)b * TV + (pbase + j)) * COUT + c0;
    us8 cv = *(const us8*)&cvb[row];
    us8 rv = *(const us8*)&resb[row];
#pragma unroll
    for (int e = 0; e < 8; ++e)
      y[j][e] = fmaxf(bf2f(cv[e]) * sct[e] + sht[e] +
                      bf2f(rv[e]) * scr[e] + shr[e], 0.f);
  }
  float* ob = &out[((long long)b * COUT + c0) * TV + pbase];
#pragma unroll
  for (int e = 0; e < 8; ++e) {
    float4 y4 = make_float4(y[0][e], y[1][e], y[2][e], y[3][e]);
    *(float4*)&ob[(long long)e * TV] = y4;
  }
}

// ---------------------------------------------------------------------------
extern "C" void kernel_launch(void* const* d_in, const int* in_sizes, int n_in,
                              void* d_out, int out_size, void* d_ws, size_t ws_size,
                              hipStream_t stream) {
  const float* x     = (const float*)d_in[0];
  const float* A_hat = (const float*)d_in[1];
  const float* w_sp  = (const float*)d_in[2];
  const float* g_sp  = (const float*)d_in[4];
  const float* be_sp = (const float*)d_in[5];
  const float* w_t   = (const float*)d_in[6];
  const float* g_t   = (const float*)d_in[8];
  const float* be_t  = (const float*)d_in[9];
  const float* w_r   = (const float*)d_in[10];
  const float* g_r   = (const float*)d_in[12];
  const float* be_r  = (const float*)d_in[13];
  float* out = (float*)d_out;

  // workspace carving (shorts)
  unsigned short* base_us = (unsigned short*)d_ws;
  unsigned short* resb = base_us;                          // TOTAL ([b][pos][c])
  unsigned short* h    = base_us + (size_t)TOTAL;          // TOTAL ([b][pos][c])
  unsigned short* cvb  = base_us + (size_t)(2 * TOTAL);    // TOTAL ([b][pos][c])
  unsigned short* wb2  = base_us + (size_t)(3 * TOTAL);    // 147456
  unsigned short* wrs2 = wb2 + 147456;                     // 16384
  unsigned short* bdt  = wrs2 + 16384;                     // 14336
  float2* part_rs = (float2*)(bdt + 14336);                // 2400*4*64
  float2* part_t  = part_rs + 2400 * 4 * 64;               // 1280*8*64
  float*  scales  = (float*)(part_t + 1280 * 8 * 64);      // 768 floats

  // all prep in one launch
  kPrep<<<696, 256, 0, stream>>>(w_t, w_r, w_sp, A_hat, wb2, wrs2, bdt);
  // spatial front-end (stats fused, 5 blocks/CU)
  kA5<<<dim3(75, 32), 256, 0, stream>>>(x, bdt, wrs2, resb, h, part_rs);
  kC2v2<<<256, 256, 0, stream>>>(part_rs, g_r, be_r, g_sp, be_sp, scales);
  // temporal conv (NP=192, 3 blocks/CU, fused BN_s+ReLU staging, stats fused)
  kE8<<<dim3(40, 32), 512, 0, stream>>>(h, wb2, scales, cvb, part_t);
  kG2<<<128, 256, 0, stream>>>(part_t, g_t, be_t, scales);
  // fused epilogue (float4 coalesced)
  kH2<<<3840, 256, 0, stream>>>(cvb, resb, scales, out);
}

// Round 11
// 308.025 us; speedup vs baseline: 1.7725x; 1.7725x over previous
//
#include <hip/hip_runtime.h>

// Problem constants
constexpr int B    = 32;
constexpr int CIN  = 64;
constexpr int COUT = 128;
constexpr int T    = 300;
constexpr int V    = 25;
constexpr int TV   = T * V;            // 7500
constexpr long long NPC   = (long long)B * TV;          // 240000 per channel
constexpr long long TOTAL = (long long)B * COUT * TV;   // 30,720,000

typedef short          bf16x8 __attribute__((ext_vector_type(8)));
typedef float          f32x4  __attribute__((ext_vector_type(4)));
typedef unsigned short us8    __attribute__((ext_vector_type(8)));
typedef unsigned short us4    __attribute__((ext_vector_type(4)));

static __device__ __forceinline__ unsigned short f2bf(float f) {
  union { float f; unsigned u; } x; x.f = f;
  unsigned r = x.u + 0x7FFFu + ((x.u >> 16) & 1u);   // RNE
  return (unsigned short)(r >> 16);
}
static __device__ __forceinline__ float bf2f(unsigned short u) {
  union { unsigned u; float f; } x; x.u = ((unsigned)u) << 16;
  return x.f;
}

// swizzled offsets (verified rounds 4-10)
static __device__ __forceinline__ int xoff(int pos, int c) {      // [pos][c<64]
  return pos * 64 + ((((c >> 3)) ^ (pos & 7)) << 3) + (c & 7);
}
static __device__ __forceinline__ int soff(int c, int pw) {       // [c][pw<128]
  return c * 128 + ((((pw >> 3)) ^ (c & 7)) << 3) + (pw & 7);
}

// ---------------------------------------------------------------------------
// kPrep: all weight/graph-matrix prep in one launch. 696 blocks x 256.
// ---------------------------------------------------------------------------
__global__ __launch_bounds__(256) void kPrep(
    const float* __restrict__ w_t, const float* __restrict__ w_r,
    const float* __restrict__ w_sp, const float* __restrict__ A_hat,
    unsigned short* __restrict__ wb2, unsigned short* __restrict__ wrs2,
    unsigned short* __restrict__ bdt)
{
  int i = blockIdx.x * 256 + threadIdx.x;
  if (i < 147456) {
    int c = i & 127, ok = i >> 7;
    int k = ok % 9, o = ok / 9;
    int idx = ((k * 16 + (c >> 3)) * 128 + o) * 8 + (c & 7);
    wb2[idx] = f2bf(w_t[(o * COUT + c) * 9 + k]);
  } else if (i < 147456 + 16384) {
    int j = i - 147456;
    int c = j & 63, row = j >> 6;
    float v = (row < COUT) ? w_r[row * CIN + c] : w_sp[(row - COUT) * CIN + c];
    wrs2[((c >> 3) * 256 + row) * 8 + (c & 7)] = f2bf(v);
  } else {
    int j = i - 147456 - 16384;
    int pv = j >> 7, pw = j & 127;
    float v = 0.f;
    if (pv < 100 && pw < 100 && (pv / 25) == (pw / 25))
      v = A_hat[(pv % 25) * 25 + (pw % 25)];
    bdt[j] = f2bf(v);
  }
}

// ---------------------------------------------------------------------------
// kA5b: all-MFMA spatial front-end + fused BN-stats partials.
// LDS alias (30.7KB), BOTH outputs [b][pos][c] us4-packed, transpose-
// butterfly stats. launch_bounds (256,2): cap 256 regs -> NO SPILL (r10
// lesson: (256,5) capped at ~102 and spilled acc[4][7]). grid (75, 32).
// ---------------------------------------------------------------------------
__global__ __launch_bounds__(256, 2) void kA5b(
    const float* __restrict__ x, const unsigned short* __restrict__ bdt,
    const unsigned short* __restrict__ wrs2,
    unsigned short* __restrict__ resb, unsigned short* __restrict__ h,
    float2* __restrict__ part_rs)
{
  __shared__ unsigned short xs[64 * 128];    // 16KB; reused as axsp after S2
  __shared__ unsigned short xsp[112 * 64];   // 14KB
  unsigned short* axsp = xs;                 // alias: axsp[pv][c] 112x64

  const int tid  = threadIdx.x;
  const int lane = tid & 63;
  const int wave = tid >> 6;
  const int b    = blockIdx.y;
  const int p0   = blockIdx.x * 100;
  const int grp  = lane >> 4;
  const int l15  = lane & 15;

  for (int u = tid; u < 16 * 128; u += 256) {
    int pos = u & 127, c4 = u >> 7;
    int c0 = c4 * 4;
    float v0 = 0.f, v1 = 0.f, v2 = 0.f, v3 = 0.f;
    if (pos < 100) {
      const float* xp = &x[(b * CIN + c0) * TV + p0 + pos];
      v0 = xp[0]; v1 = xp[TV]; v2 = xp[2 * TV]; v3 = xp[3 * TV];
    }
    unsigned short b0 = f2bf(v0), b1 = f2bf(v1), b2 = f2bf(v2), b3 = f2bf(v3);
    xs[soff(c0,     pos)] = b0;
    xs[soff(c0 + 1, pos)] = b1;
    xs[soff(c0 + 2, pos)] = b2;
    xs[soff(c0 + 3, pos)] = b3;
    if (pos < 112) {
      us4 pk = {b0, b1, b2, b3};
      *(us4*)&xsp[xoff(pos, c0)] = pk;
    }
  }
  __syncthreads();                       // S1: staging done

  bf16x8 xf[4];
#pragma unroll
  for (int ks = 0; ks < 4; ++ks)
    xf[ks] = *(const bf16x8*)&xs[soff(wave * 16 + l15, ks * 32 + grp * 8)];
  __syncthreads();                       // S2: xf in regs; xs reusable

  // mix GEMM (sparse block-diagonal k-steps, table VERIFIED round 5)
  {
    f32x4 macc[7];
#pragma unroll
    for (int ni = 0; ni < 7; ++ni) macc[ni] = (f32x4)0.f;
    const int kst[7] = {0, 0, 0, 0, 1, 2, 2};
    const int kcn[7] = {1, 2, 2, 3, 3, 2, 2};
#pragma unroll
    for (int ni = 0; ni < 7; ++ni) {
      for (int kk = 0; kk < kcn[ni]; ++kk) {
        int ks = kst[ni] + kk;
        bf16x8 gf = *(const bf16x8*)&bdt[(ni * 16 + l15) * 128 + ks * 32 + grp * 8];
        macc[ni] = __builtin_amdgcn_mfma_f32_16x16x32_bf16(xf[ks], gf, macc[ni], 0, 0, 0);
      }
    }
#pragma unroll
    for (int ni = 0; ni < 7; ++ni) {
#pragma unroll
      for (int r = 0; r < 4; ++r)
        axsp[xoff(ni * 16 + l15, wave * 16 + grp * 4 + r)] = f2bf(macc[ni][r]);
    }
  }
  __syncthreads();                       // S3: axsp ready

  const unsigned short* bsrc = (wave < 2) ? xsp : axsp;
  f32x4 acc[4][7];
#pragma unroll
  for (int m = 0; m < 4; ++m)
#pragma unroll
    for (int n = 0; n < 7; ++n) acc[m][n] = (f32x4)0.f;

#pragma unroll
  for (int ks = 0; ks < 2; ++ks) {
    bf16x8 af[4], bfr[7];
#pragma unroll
    for (int mi = 0; mi < 4; ++mi) {
      int row = wave * 64 + mi * 16 + l15;
      af[mi] = *(const bf16x8*)&wrs2[((ks * 4 + grp) * 256 + row) * 8];
    }
#pragma unroll
    for (int ni = 0; ni < 7; ++ni)
      bfr[ni] = *(const bf16x8*)&bsrc[xoff(ni * 16 + l15, ks * 32 + grp * 8)];
#pragma unroll
    for (int mi = 0; mi < 4; ++mi)
#pragma unroll
      for (int ni = 0; ni < 7; ++ni)
        acc[mi][ni] = __builtin_amdgcn_mfma_f32_16x16x32_bf16(
            af[mi], bfr[ni], acc[mi][ni], 0, 0, 0);
  }

  // epilogue: us4 packs, [b][pos][c] layout for BOTH outputs
  {
    unsigned short* dst = (wave < 2) ? resb : h;
#pragma unroll
    for (int mi = 0; mi < 4; ++mi) {
      const int c0 = (wave & 1) * 64 + mi * 16 + grp * 4;
#pragma unroll
      for (int ni = 0; ni < 7; ++ni) {
        int pos = ni * 16 + l15;
        if (pos < 100) {
          us4 pk;
#pragma unroll
          for (int r = 0; r < 4; ++r) pk[r] = f2bf(acc[mi][ni][r]);
          *(us4*)&dst[((long long)(b * TV + p0 + pos)) * COUT + c0] = pk;
        }
      }
    }
  }

  // fused BN stats: transpose-butterfly (15 pair-steps), all lanes store
  {
    float sv[16], qv[16];
#pragma unroll
    for (int mi = 0; mi < 4; ++mi)
#pragma unroll
      for (int r = 0; r < 4; ++r) {
        float s = 0.f, q = 0.f;
#pragma unroll
        for (int ni = 0; ni < 7; ++ni) {
          float v = (ni < 6 || l15 < 4) ? acc[mi][ni][r] : 0.f;  // pos<100
          s += v; q += v * v;
        }
        sv[mi * 4 + r] = s; qv[mi * 4 + r] = q;
      }
#pragma unroll
    for (int bm = 1; bm < 16; bm <<= 1) {
      const bool up = (l15 & bm) != 0;
#pragma unroll
      for (int i = 0; i < 16; i += 2 * bm) {
        const int j = i + bm;
        float ssend = up ? sv[i] : sv[j];
        float qsend = up ? qv[i] : qv[j];
        float sgot = __shfl_xor(ssend, bm);
        float qgot = __shfl_xor(qsend, bm);
        sv[i] = (up ? sv[j] : sv[i]) + sgot;
        qv[i] = (up ? qv[j] : qv[i]) + qgot;
      }
    }
    // lane l15 holds (s,q) for mi = l15>>2, r = l15&3
    int slot = ((l15 >> 2) * 16) + grp * 4 + (l15 & 3);
    float2* pw = &part_rs[(((long long)(blockIdx.y * 75 + blockIdx.x)) * 4 + wave) * 64];
    pw[slot] = make_float2(sv[0], qv[0]);
  }
}

// ---------------------------------------------------------------------------
// kC2v2: finalize res & sp BN from kA5b partials. grid 256.
// scales: [0]=sc_r [128]=sh_r [256]=sc_s [384]=sh_s [512]=sc_t [640]=sh_t
// ---------------------------------------------------------------------------
__global__ __launch_bounds__(256) void kC2v2(
    const float2* __restrict__ part_rs,
    const float* __restrict__ g_r,  const float* __restrict__ be_r,
    const float* __restrict__ g_sp, const float* __restrict__ be_sp,
    float* __restrict__ scales)
{
  __shared__ float rs[256], rq[256];
  const int row = blockIdx.x;
  const int wave = row >> 6, local = row & 63;
  const int tid = threadIdx.x;
  float s = 0.f, q = 0.f;
  for (int bid = tid; bid < 2400; bid += 256) {
    float2 v = part_rs[((long long)bid * 4 + wave) * 64 + local];
    s += v.x; q += v.y;
  }
  rs[tid] = s; rq[tid] = q;
  __syncthreads();
  for (int st = 128; st > 0; st >>= 1) {
    if (tid < st) { rs[tid] += rs[tid + st]; rq[tid] += rq[tid + st]; }
    __syncthreads();
  }
  if (tid == 0) {
    const float n = (float)NPC;
    float m = rs[0] / n, var = rq[0] / n - m * m;
    float iv = rsqrtf(var + 1e-5f);
    if (row < 128) {
      float sc = g_r[row] * iv;
      scales[row] = sc; scales[128 + row] = be_r[row] - m * sc;
    } else {
      int c = row - 128;
      float sc = g_sp[c] * iv;
      scales[256 + c] = sc; scales[384 + c] = be_sp[c] - m * sc;
    }
  }
}

// ---------------------------------------------------------------------------
// kE7b: temporal conv 9x1, implicit MFMA GEMM. NP=256 tile, 512 threads /
// 8 waves (2 wm x 4 wn), single 58KB LDS buffer, launch_bounds (512,2)
// (cap 256 regs, no spill; LDS-limited 2 blocks/CU -- r9 proven).
// BN_s+ReLU fused in swizzled staging (0 conflicts); cvb [b][pos][c]
// us4-packed; transpose-butterfly BN_t stats; setprio. grid (30, 32).
// ---------------------------------------------------------------------------
constexpr int NP    = 256;
constexpr int HALO  = 100;               // 4*25
constexpr int STAGE = NP + 2 * HALO;     // 456

__global__ __launch_bounds__(512, 2) void kE7b(
    const unsigned short* __restrict__ h, const unsigned short* __restrict__ wb2,
    const float* __restrict__ scales, unsigned short* __restrict__ cvb,
    float2* __restrict__ part_t)
{
  __shared__ unsigned short hs[STAGE * 64];   // 58368 B
  const int tid  = threadIdx.x;
  const int lane = tid & 63;
  const int wave = tid >> 6;          // 0..7
  const int wm   = wave >> 2, wn = wave & 3;
  const int b    = blockIdx.y;
  const int p0   = blockIdx.x * NP;
  const int grp  = lane >> 4;
  const int l15  = lane & 15;
  const int slot = tid & 7;

  f32x4 acc[4][4];
#pragma unroll
  for (int m = 0; m < 4; ++m)
#pragma unroll
    for (int n = 0; n < 4; ++n) acc[m][n] = (f32x4)0.f;

  for (int cc = 0; cc < 2; ++cc) {
    if (cc) __syncthreads();             // prev chunk's MFMA reads done
    const int c0 = cc * 64;
    float sc[8], sh[8];
#pragma unroll
    for (int e = 0; e < 8; ++e) {
      sc[e] = scales[256 + c0 + slot * 8 + e];
      sh[e] = scales[384 + c0 + slot * 8 + e];
    }
    for (int i = tid; i < STAGE * 8; i += 512) {
      int pos = i >> 3;
      int pg = p0 - HALO + pos;
      us8 o = (us8)(unsigned short)0;
      if (pg >= 0 && pg < TV) {
        us8 v = *(const us8*)&h[((long long)b * TV + pg) * COUT + c0 + slot * 8];
#pragma unroll
        for (int e = 0; e < 8; ++e)
          o[e] = f2bf(fmaxf(bf2f(v[e]) * sc[e] + sh[e], 0.f));
      }
      int si = (pos << 6) + ((slot ^ (pos & 7)) << 3);
      *(us8*)&hs[si] = o;
    }
    __syncthreads();

    __builtin_amdgcn_s_setprio(1);
    for (int k = 0; k < 9; ++k) {
      const int plb = HALO + wn * 64 + 25 * (k - 4) + l15;
#pragma unroll
      for (int ks = 0; ks < 2; ++ks) {
        bf16x8 af[4], bfr[4];
#pragma unroll
        for (int mi = 0; mi < 4; ++mi) {
          int o = wm * 64 + mi * 16 + l15;
          af[mi] = *(const bf16x8*)&wb2[((k * 16 + cc * 8 + ks * 4 + grp) * 128 + o) * 8];
        }
#pragma unroll
        for (int ni = 0; ni < 4; ++ni) {
          int pl = plb + ni * 16;
          int si = (pl << 6) + (((ks * 4 + grp) ^ (pl & 7)) << 3);
          bfr[ni] = *(const bf16x8*)&hs[si];
        }
#pragma unroll
        for (int mi = 0; mi < 4; ++mi)
#pragma unroll
          for (int ni = 0; ni < 4; ++ni)
            acc[mi][ni] = __builtin_amdgcn_mfma_f32_16x16x32_bf16(
                af[mi], bfr[ni], acc[mi][ni], 0, 0, 0);
      }
    }
    __builtin_amdgcn_s_setprio(0);
  }

  // epilogue: conv -> cvb bf16, [b][pos][c] us4-packed
#pragma unroll
  for (int mi = 0; mi < 4; ++mi) {
    const int c0 = wm * 64 + mi * 16 + grp * 4;
#pragma unroll
    for (int ni = 0; ni < 4; ++ni) {
      int pos = p0 + wn * 64 + ni * 16 + l15;
      if (pos < TV) {
        us4 pk;
#pragma unroll
        for (int r = 0; r < 4; ++r) pk[r] = f2bf(acc[mi][ni][r]);
        *(us4*)&cvb[((long long)(b * TV + pos)) * COUT + c0] = pk;
      }
    }
  }

  // fused BN_t stats: transpose-butterfly, [bid][wave(8)][64]
  {
    float sv[16], qv[16];
#pragma unroll
    for (int mi = 0; mi < 4; ++mi)
#pragma unroll
      for (int r = 0; r < 4; ++r) {
        float s = 0.f, q = 0.f;
#pragma unroll
        for (int ni = 0; ni < 4; ++ni) {
          int pos = p0 + wn * 64 + ni * 16 + l15;
          float v = (pos < TV) ? acc[mi][ni][r] : 0.f;
          s += v; q += v * v;
        }
        sv[mi * 4 + r] = s; qv[mi * 4 + r] = q;
      }
#pragma unroll
    for (int bm = 1; bm < 16; bm <<= 1) {
      const bool up = (l15 & bm) != 0;
#pragma unroll
      for (int i = 0; i < 16; i += 2 * bm) {
        const int j = i + bm;
        float ssend = up ? sv[i] : sv[j];
        float qsend = up ? qv[i] : qv[j];
        float sgot = __shfl_xor(ssend, bm);
        float qgot = __shfl_xor(qsend, bm);
        sv[i] = (up ? sv[j] : sv[i]) + sgot;
        qv[i] = (up ? qv[j] : qv[i]) + qgot;
      }
    }
    int slt = ((l15 >> 2) * 16) + grp * 4 + (l15 & 3);
    float2* pw = &part_t[(((long long)(blockIdx.y * 30 + blockIdx.x)) * 8 + wave) * 64];
    pw[slt] = make_float2(sv[0], qv[0]);
  }
}

// ---------------------------------------------------------------------------
// kG2: finalize temporal BN from kE7b partials. grid 128.
// channel c = wm*64 + local; waves wm*4+wn (wn 0..3) of 960 blocks.
// ---------------------------------------------------------------------------
__global__ __launch_bounds__(256) void kG2(
    const float2* __restrict__ part_t,
    const float* __restrict__ g_t, const float* __restrict__ be_t,
    float* __restrict__ scales)
{
  __shared__ float rs[256], rq[256];
  const int c = blockIdx.x;
  const int wm = c >> 6, local = c & 63;
  const int tid = threadIdx.x;
  const int NB = 30 * 32;              // 960 blocks
  float s = 0.f, q = 0.f;
  for (int p = tid; p < NB * 4; p += 256) {
    int bid = p >> 2, wn = p & 3;
    float2 v = part_t[((long long)bid * 8 + (wm * 4 + wn)) * 64 + local];
    s += v.x; q += v.y;
  }
  rs[tid] = s; rq[tid] = q;
  __syncthreads();
  for (int st = 128; st > 0; st >>= 1) {
    if (tid < st) { rs[tid] += rs[tid + st]; rq[tid] += rq[tid + st]; }
    __syncthreads();
  }
  if (tid == 0) {
    const float n = (float)NPC;
    float m = rs[0] / n, var = rq[0] / n - m * m;
    float sc = g_t[c] * rsqrtf(var + 1e-5f);
    scales[512 + c] = sc;
    scales[640 + c] = be_t[c] - m * sc;
  }
}

// ---------------------------------------------------------------------------
// kH2: out = relu(cvb*sc_t+sh_t + resb*sc_r+sh_r); inputs [b][pos][c] bf16,
// output NCHW fp32. Lane reads 4 consecutive rows' us8 slice, writes 8
// float4 coalesced stores. grid 3840 x 256.
// ---------------------------------------------------------------------------
__global__ __launch_bounds__(256) void kH2(
    const unsigned short* __restrict__ cvb, const unsigned short* __restrict__ resb,
    const float* __restrict__ scales, float* __restrict__ out)
{
  const int tid  = threadIdx.x;
  const int lane = tid & 63;
  const int unit = blockIdx.x * 4 + (tid >> 6);   // ((b*16+slot)*30 + pt)
  const int pt   = unit % 30;
  const int rest = unit / 30;
  const int cslot = rest & 15;
  const int b    = rest >> 4;
  const int c0   = cslot * 8;
  float sct[8], sht[8], scr[8], shr[8];
#pragma unroll
  for (int e = 0; e < 8; ++e) {
    sct[e] = scales[512 + c0 + e]; sht[e] = scales[640 + c0 + e];
    scr[e] = scales[c0 + e];       shr[e] = scales[128 + c0 + e];
  }
  const int pbase = pt * 256 + lane * 4;
  if (pbase + 4 > TV) return;        // tail tile: lanes >= 19 idle
  float y[4][8];
#pragma unroll
  for (int j = 0; j < 4; ++j) {
    long long row = ((long long)b * TV + (pbase + j)) * COUT + c0;
    us8 cv = *(const us8*)&cvb[row];
    us8 rv = *(const us8*)&resb[row];
#pragma unroll
    for (int e = 0; e < 8; ++e)
      y[j][e] = fmaxf(bf2f(cv[e]) * sct[e] + sht[e] +
                      bf2f(rv[e]) * scr[e] + shr[e], 0.f);
  }
  float* ob = &out[((long long)b * COUT + c0) * TV + pbase];
#pragma unroll
  for (int e = 0; e < 8; ++e) {
    float4 y4 = make_float4(y[0][e], y[1][e], y[2][e], y[3][e]);
    *(float4*)&ob[(long long)e * TV] = y4;
  }
}

// ---------------------------------------------------------------------------
extern "C" void kernel_launch(void* const* d_in, const int* in_sizes, int n_in,
                              void* d_out, int out_size, void* d_ws, size_t ws_size,
                              hipStream_t stream) {
  const float* x     = (const float*)d_in[0];
  const float* A_hat = (const float*)d_in[1];
  const float* w_sp  = (const float*)d_in[2];
  const float* g_sp  = (const float*)d_in[4];
  const float* be_sp = (const float*)d_in[5];
  const float* w_t   = (const float*)d_in[6];
  const float* g_t   = (const float*)d_in[8];
  const float* be_t  = (const float*)d_in[9];
  const float* w_r   = (const float*)d_in[10];
  const float* g_r   = (const float*)d_in[12];
  const float* be_r  = (const float*)d_in[13];
  float* out = (float*)d_out;

  // workspace carving (shorts)
  unsigned short* base_us = (unsigned short*)d_ws;
  unsigned short* resb = base_us;                          // TOTAL ([b][pos][c])
  unsigned short* h    = base_us + (size_t)TOTAL;          // TOTAL ([b][pos][c])
  unsigned short* cvb  = base_us + (size_t)(2 * TOTAL);    // TOTAL ([b][pos][c])
  unsigned short* wb2  = base_us + (size_t)(3 * TOTAL);    // 147456
  unsigned short* wrs2 = wb2 + 147456;                     // 16384
  unsigned short* bdt  = wrs2 + 16384;                     // 14336
  float2* part_rs = (float2*)(bdt + 14336);                // 2400*4*64
  float2* part_t  = part_rs + 2400 * 4 * 64;               // 960*8*64
  float*  scales  = (float*)(part_t + 960 * 8 * 64);       // 768 floats

  // all prep in one launch
  kPrep<<<696, 256, 0, stream>>>(w_t, w_r, w_sp, A_hat, wb2, wrs2, bdt);
  // spatial front-end (stats fused)
  kA5b<<<dim3(75, 32), 256, 0, stream>>>(x, bdt, wrs2, resb, h, part_rs);
  kC2v2<<<256, 256, 0, stream>>>(part_rs, g_r, be_r, g_sp, be_sp, scales);
  // temporal conv (NP=256, fused BN_s+ReLU staging, stats fused)
  kE7b<<<dim3(30, 32), 512, 0, stream>>>(h, wb2, scales, cvb, part_t);
  kG2<<<128, 256, 0, stream>>>(part_t, g_t, be_t, scales);
  // fused epilogue (float4 coalesced)
  kH2<<<3840, 256, 0, stream>>>(cvb, resb, scales, out);
}

// Round 12
// 247.562 us; speedup vs baseline: 2.2054x; 1.2442x over previous
//
#include <hip/hip_runtime.h>

// Problem constants
constexpr int B    = 32;
constexpr int CIN  = 64;
constexpr int COUT = 128;
constexpr int T    = 300;
constexpr int V    = 25;
constexpr int TV   = T * V;            // 7500
constexpr long long NPC   = (long long)B * TV;          // 240000 per channel
constexpr long long TOTAL = (long long)B * COUT * TV;   // 30,720,000

typedef short          bf16x8 __attribute__((ext_vector_type(8)));
typedef float          f32x4  __attribute__((ext_vector_type(4)));
typedef unsigned short us8    __attribute__((ext_vector_type(8)));
typedef unsigned short us4    __attribute__((ext_vector_type(4)));

static __device__ __forceinline__ unsigned short f2bf(float f) {
  union { float f; unsigned u; } x; x.f = f;
  unsigned r = x.u + 0x7FFFu + ((x.u >> 16) & 1u);   // RNE
  return (unsigned short)(r >> 16);
}
static __device__ __forceinline__ float bf2f(unsigned short u) {
  union { unsigned u; float f; } x; x.u = ((unsigned)u) << 16;
  return x.f;
}

// swizzled offsets (verified rounds 4-11)
static __device__ __forceinline__ int xoff(int pos, int c) {      // [pos][c<64]
  return pos * 64 + ((((c >> 3)) ^ (pos & 7)) << 3) + (c & 7);
}
static __device__ __forceinline__ int soff(int c, int pw) {       // [c][pw<128]
  return c * 128 + ((((pw >> 3)) ^ (c & 7)) << 3) + (pw & 7);
}

// ---------------------------------------------------------------------------
// kPrep: all weight/graph-matrix prep in one launch. 696 blocks x 256.
// ---------------------------------------------------------------------------
__global__ __launch_bounds__(256) void kPrep(
    const float* __restrict__ w_t, const float* __restrict__ w_r,
    const float* __restrict__ w_sp, const float* __restrict__ A_hat,
    unsigned short* __restrict__ wb2, unsigned short* __restrict__ wrs2,
    unsigned short* __restrict__ bdt)
{
  int i = blockIdx.x * 256 + threadIdx.x;
  if (i < 147456) {
    int c = i & 127, ok = i >> 7;
    int k = ok % 9, o = ok / 9;
    int idx = ((k * 16 + (c >> 3)) * 128 + o) * 8 + (c & 7);
    wb2[idx] = f2bf(w_t[(o * COUT + c) * 9 + k]);
  } else if (i < 147456 + 16384) {
    int j = i - 147456;
    int c = j & 63, row = j >> 6;
    float v = (row < COUT) ? w_r[row * CIN + c] : w_sp[(row - COUT) * CIN + c];
    wrs2[((c >> 3) * 256 + row) * 8 + (c & 7)] = f2bf(v);
  } else {
    int j = i - 147456 - 16384;
    int pv = j >> 7, pw = j & 127;
    float v = 0.f;
    if (pv < 100 && pw < 100 && (pv / 25) == (pw / 25))
      v = A_hat[(pv % 25) * 25 + (pw % 25)];
    bdt[j] = f2bf(v);
  }
}

// ---------------------------------------------------------------------------
// kA6: all-MFMA spatial front-end + fused BN-stats partials.
// = r9 kA4 structure/layouts + LDS alias (30.7KB) + transpose-butterfly
// stats (both measured wins in r11). Outputs: resb [b][c][pos] (scalar,
// for plane-kH), h [b][pos][c] us4 (for kE staging). grid (75, 32).
// ---------------------------------------------------------------------------
__global__ __launch_bounds__(256, 2) void kA6(
    const float* __restrict__ x, const unsigned short* __restrict__ bdt,
    const unsigned short* __restrict__ wrs2,
    unsigned short* __restrict__ resb, unsigned short* __restrict__ h,
    float2* __restrict__ part_rs)
{
  __shared__ unsigned short xs[64 * 128];    // 16KB; reused as axsp after S2
  __shared__ unsigned short xsp[112 * 64];   // 14KB
  unsigned short* axsp = xs;                 // alias: axsp[pv][c] 112x64

  const int tid  = threadIdx.x;
  const int lane = tid & 63;
  const int wave = tid >> 6;
  const int b    = blockIdx.y;
  const int p0   = blockIdx.x * 100;
  const int grp  = lane >> 4;
  const int l15  = lane & 15;

  for (int u = tid; u < 16 * 128; u += 256) {
    int pos = u & 127, c4 = u >> 7;
    int c0 = c4 * 4;
    float v0 = 0.f, v1 = 0.f, v2 = 0.f, v3 = 0.f;
    if (pos < 100) {
      const float* xp = &x[(b * CIN + c0) * TV + p0 + pos];
      v0 = xp[0]; v1 = xp[TV]; v2 = xp[2 * TV]; v3 = xp[3 * TV];
    }
    unsigned short b0 = f2bf(v0), b1 = f2bf(v1), b2 = f2bf(v2), b3 = f2bf(v3);
    xs[soff(c0,     pos)] = b0;
    xs[soff(c0 + 1, pos)] = b1;
    xs[soff(c0 + 2, pos)] = b2;
    xs[soff(c0 + 3, pos)] = b3;
    if (pos < 112) {
      us4 pk = {b0, b1, b2, b3};
      *(us4*)&xsp[xoff(pos, c0)] = pk;
    }
  }
  __syncthreads();                       // S1: staging done

  bf16x8 xf[4];
#pragma unroll
  for (int ks = 0; ks < 4; ++ks)
    xf[ks] = *(const bf16x8*)&xs[soff(wave * 16 + l15, ks * 32 + grp * 8)];
  __syncthreads();                       // S2: xf in regs; xs reusable

  // mix GEMM (sparse block-diagonal k-steps, table VERIFIED round 5)
  {
    f32x4 macc[7];
#pragma unroll
    for (int ni = 0; ni < 7; ++ni) macc[ni] = (f32x4)0.f;
    const int kst[7] = {0, 0, 0, 0, 1, 2, 2};
    const int kcn[7] = {1, 2, 2, 3, 3, 2, 2};
#pragma unroll
    for (int ni = 0; ni < 7; ++ni) {
      for (int kk = 0; kk < kcn[ni]; ++kk) {
        int ks = kst[ni] + kk;
        bf16x8 gf = *(const bf16x8*)&bdt[(ni * 16 + l15) * 128 + ks * 32 + grp * 8];
        macc[ni] = __builtin_amdgcn_mfma_f32_16x16x32_bf16(xf[ks], gf, macc[ni], 0, 0, 0);
      }
    }
#pragma unroll
    for (int ni = 0; ni < 7; ++ni) {
#pragma unroll
      for (int r = 0; r < 4; ++r)
        axsp[xoff(ni * 16 + l15, wave * 16 + grp * 4 + r)] = f2bf(macc[ni][r]);
    }
  }
  __syncthreads();                       // S3: axsp ready

  const unsigned short* bsrc = (wave < 2) ? xsp : axsp;
  f32x4 acc[4][7];
#pragma unroll
  for (int m = 0; m < 4; ++m)
#pragma unroll
    for (int n = 0; n < 7; ++n) acc[m][n] = (f32x4)0.f;

#pragma unroll
  for (int ks = 0; ks < 2; ++ks) {
    bf16x8 af[4], bfr[7];
#pragma unroll
    for (int mi = 0; mi < 4; ++mi) {
      int row = wave * 64 + mi * 16 + l15;
      af[mi] = *(const bf16x8*)&wrs2[((ks * 4 + grp) * 256 + row) * 8];
    }
#pragma unroll
    for (int ni = 0; ni < 7; ++ni)
      bfr[ni] = *(const bf16x8*)&bsrc[xoff(ni * 16 + l15, ks * 32 + grp * 8)];
#pragma unroll
    for (int mi = 0; mi < 4; ++mi)
#pragma unroll
      for (int ni = 0; ni < 7; ++ni)
        acc[mi][ni] = __builtin_amdgcn_mfma_f32_16x16x32_bf16(
            af[mi], bfr[ni], acc[mi][ni], 0, 0, 0);
  }

  // epilogue (r9 layouts): resb scalar [b][c][pos]; h us4 [b][pos][c]
  if (wave < 2) {
#pragma unroll
    for (int mi = 0; mi < 4; ++mi) {
#pragma unroll
      for (int ni = 0; ni < 7; ++ni) {
        int pos = ni * 16 + l15;
        if (pos < 100) {
#pragma unroll
          for (int r = 0; r < 4; ++r) {
            int c = wave * 64 + mi * 16 + grp * 4 + r;
            resb[((long long)(b * COUT + c)) * TV + p0 + pos] = f2bf(acc[mi][ni][r]);
          }
        }
      }
    }
  } else {
#pragma unroll
    for (int mi = 0; mi < 4; ++mi) {
      int o0 = (wave - 2) * 64 + mi * 16 + grp * 4;
#pragma unroll
      for (int ni = 0; ni < 7; ++ni) {
        int pos = ni * 16 + l15;
        if (pos < 100) {
          us4 pk;
#pragma unroll
          for (int r = 0; r < 4; ++r) pk[r] = f2bf(acc[mi][ni][r]);
          *(us4*)&h[((long long)(b * TV + p0 + pos)) * COUT + o0] = pk;
        }
      }
    }
  }

  // fused BN stats: transpose-butterfly (verified r11)
  {
    float sv[16], qv[16];
#pragma unroll
    for (int mi = 0; mi < 4; ++mi)
#pragma unroll
      for (int r = 0; r < 4; ++r) {
        float s = 0.f, q = 0.f;
#pragma unroll
        for (int ni = 0; ni < 7; ++ni) {
          float v = (ni < 6 || l15 < 4) ? acc[mi][ni][r] : 0.f;  // pos<100
          s += v; q += v * v;
        }
        sv[mi * 4 + r] = s; qv[mi * 4 + r] = q;
      }
#pragma unroll
    for (int bm = 1; bm < 16; bm <<= 1) {
      const bool up = (l15 & bm) != 0;
#pragma unroll
      for (int i = 0; i < 16; i += 2 * bm) {
        const int j = i + bm;
        float ssend = up ? sv[i] : sv[j];
        float qsend = up ? qv[i] : qv[j];
        float sgot = __shfl_xor(ssend, bm);
        float qgot = __shfl_xor(qsend, bm);
        sv[i] = (up ? sv[j] : sv[i]) + sgot;
        qv[i] = (up ? qv[j] : qv[i]) + qgot;
      }
    }
    // lane l15 holds (s,q) for mi=l15>>2, r=l15&3 -> slot = mi*16+grp*4+r
    int slot = ((l15 >> 2) * 16) + grp * 4 + (l15 & 3);
    float2* pw = &part_rs[(((long long)(blockIdx.y * 75 + blockIdx.x)) * 4 + wave) * 64];
    pw[slot] = make_float2(sv[0], qv[0]);
  }
}

// ---------------------------------------------------------------------------
// kC2v2: finalize res & sp BN from kA6 partials. grid 256.
// scales: [0]=sc_r [128]=sh_r [256]=sc_s [384]=sh_s [512]=sc_t [640]=sh_t
// ---------------------------------------------------------------------------
__global__ __launch_bounds__(256) void kC2v2(
    const float2* __restrict__ part_rs,
    const float* __restrict__ g_r,  const float* __restrict__ be_r,
    const float* __restrict__ g_sp, const float* __restrict__ be_sp,
    float* __restrict__ scales)
{
  __shared__ float rs[256], rq[256];
  const int row = blockIdx.x;
  const int wave = row >> 6, local = row & 63;
  const int tid = threadIdx.x;
  float s = 0.f, q = 0.f;
  for (int bid = tid; bid < 2400; bid += 256) {
    float2 v = part_rs[((long long)bid * 4 + wave) * 64 + local];
    s += v.x; q += v.y;
  }
  rs[tid] = s; rq[tid] = q;
  __syncthreads();
  for (int st = 128; st > 0; st >>= 1) {
    if (tid < st) { rs[tid] += rs[tid + st]; rq[tid] += rq[tid + st]; }
    __syncthreads();
  }
  if (tid == 0) {
    const float n = (float)NPC;
    float m = rs[0] / n, var = rq[0] / n - m * m;
    float iv = rsqrtf(var + 1e-5f);
    if (row < 128) {
      float sc = g_r[row] * iv;
      scales[row] = sc; scales[128 + row] = be_r[row] - m * sc;
    } else {
      int c = row - 128;
      float sc = g_sp[c] * iv;
      scales[256 + c] = sc; scales[384 + c] = be_sp[c] - m * sc;
    }
  }
}

// ---------------------------------------------------------------------------
// kE7c: temporal conv 9x1, implicit MFMA GEMM. NP=256, 512 threads / 8
// waves, single 58KB LDS buffer (r9-proven structure). BN_s+ReLU fused in
// swizzled staging (0 conflicts); cvb scalar [b][c][pos] (32B-aligned
// segments: p0=256*bx); butterfly BN_t stats; setprio. grid (30, 32).
// ---------------------------------------------------------------------------
constexpr int NP    = 256;
constexpr int HALO  = 100;               // 4*25
constexpr int STAGE = NP + 2 * HALO;     // 456

__global__ __launch_bounds__(512, 2) void kE7c(
    const unsigned short* __restrict__ h, const unsigned short* __restrict__ wb2,
    const float* __restrict__ scales, unsigned short* __restrict__ cvb,
    float2* __restrict__ part_t)
{
  __shared__ unsigned short hs[STAGE * 64];   // 58368 B
  const int tid  = threadIdx.x;
  const int lane = tid & 63;
  const int wave = tid >> 6;          // 0..7
  const int wm   = wave >> 2, wn = wave & 3;
  const int b    = blockIdx.y;
  const int p0   = blockIdx.x * NP;
  const int grp  = lane >> 4;
  const int l15  = lane & 15;
  const int slot = tid & 7;

  f32x4 acc[4][4];
#pragma unroll
  for (int m = 0; m < 4; ++m)
#pragma unroll
    for (int n = 0; n < 4; ++n) acc[m][n] = (f32x4)0.f;

  for (int cc = 0; cc < 2; ++cc) {
    if (cc) __syncthreads();             // prev chunk's MFMA reads done
    const int c0 = cc * 64;
    float sc[8], sh[8];
#pragma unroll
    for (int e = 0; e < 8; ++e) {
      sc[e] = scales[256 + c0 + slot * 8 + e];
      sh[e] = scales[384 + c0 + slot * 8 + e];
    }
    for (int i = tid; i < STAGE * 8; i += 512) {
      int pos = i >> 3;
      int pg = p0 - HALO + pos;
      us8 o = (us8)(unsigned short)0;
      if (pg >= 0 && pg < TV) {
        us8 v = *(const us8*)&h[((long long)b * TV + pg) * COUT + c0 + slot * 8];
#pragma unroll
        for (int e = 0; e < 8; ++e)
          o[e] = f2bf(fmaxf(bf2f(v[e]) * sc[e] + sh[e], 0.f));
      }
      int si = (pos << 6) + ((slot ^ (pos & 7)) << 3);
      *(us8*)&hs[si] = o;
    }
    __syncthreads();

    __builtin_amdgcn_s_setprio(1);
    for (int k = 0; k < 9; ++k) {
      const int plb = HALO + wn * 64 + 25 * (k - 4) + l15;
#pragma unroll
      for (int ks = 0; ks < 2; ++ks) {
        bf16x8 af[4], bfr[4];
#pragma unroll
        for (int mi = 0; mi < 4; ++mi) {
          int o = wm * 64 + mi * 16 + l15;
          af[mi] = *(const bf16x8*)&wb2[((k * 16 + cc * 8 + ks * 4 + grp) * 128 + o) * 8];
        }
#pragma unroll
        for (int ni = 0; ni < 4; ++ni) {
          int pl = plb + ni * 16;
          int si = (pl << 6) + (((ks * 4 + grp) ^ (pl & 7)) << 3);
          bfr[ni] = *(const bf16x8*)&hs[si];
        }
#pragma unroll
        for (int mi = 0; mi < 4; ++mi)
#pragma unroll
          for (int ni = 0; ni < 4; ++ni)
            acc[mi][ni] = __builtin_amdgcn_mfma_f32_16x16x32_bf16(
                af[mi], bfr[ni], acc[mi][ni], 0, 0, 0);
      }
    }
    __builtin_amdgcn_s_setprio(0);
  }

  // epilogue: conv -> cvb bf16, [b][c][pos] scalar (r9 layout, for plane-kH)
#pragma unroll
  for (int mi = 0; mi < 4; ++mi) {
#pragma unroll
    for (int ni = 0; ni < 4; ++ni) {
      int pos = p0 + wn * 64 + ni * 16 + l15;
      if (pos < TV) {
#pragma unroll
        for (int r = 0; r < 4; ++r) {
          int o = wm * 64 + mi * 16 + grp * 4 + r;
          cvb[((long long)(b * COUT + o)) * TV + pos] = f2bf(acc[mi][ni][r]);
        }
      }
    }
  }

  // fused BN_t stats: transpose-butterfly, [bid][wave(8)][64]
  {
    float sv[16], qv[16];
#pragma unroll
    for (int mi = 0; mi < 4; ++mi)
#pragma unroll
      for (int r = 0; r < 4; ++r) {
        float s = 0.f, q = 0.f;
#pragma unroll
        for (int ni = 0; ni < 4; ++ni) {
          int pos = p0 + wn * 64 + ni * 16 + l15;
          float v = (pos < TV) ? acc[mi][ni][r] : 0.f;
          s += v; q += v * v;
        }
        sv[mi * 4 + r] = s; qv[mi * 4 + r] = q;
      }
#pragma unroll
    for (int bm = 1; bm < 16; bm <<= 1) {
      const bool up = (l15 & bm) != 0;
#pragma unroll
      for (int i = 0; i < 16; i += 2 * bm) {
        const int j = i + bm;
        float ssend = up ? sv[i] : sv[j];
        float qsend = up ? qv[i] : qv[j];
        float sgot = __shfl_xor(ssend, bm);
        float qgot = __shfl_xor(qsend, bm);
        sv[i] = (up ? sv[j] : sv[i]) + sgot;
        qv[i] = (up ? qv[j] : qv[i]) + qgot;
      }
    }
    int slt = ((l15 >> 2) * 16) + grp * 4 + (l15 & 3);
    float2* pw = &part_t[(((long long)(blockIdx.y * 30 + blockIdx.x)) * 8 + wave) * 64];
    pw[slt] = make_float2(sv[0], qv[0]);
  }
}

// ---------------------------------------------------------------------------
// kG2: finalize temporal BN from kE7c partials. grid 128.
// channel c = wm*64 + local; waves wm*4+wn (wn 0..3) of 960 blocks.
// ---------------------------------------------------------------------------
__global__ __launch_bounds__(256) void kG2(
    const float2* __restrict__ part_t,
    const float* __restrict__ g_t, const float* __restrict__ be_t,
    float* __restrict__ scales)
{
  __shared__ float rs[256], rq[256];
  const int c = blockIdx.x;
  const int wm = c >> 6, local = c & 63;
  const int tid = threadIdx.x;
  const int NB = 30 * 32;              // 960 blocks
  float s = 0.f, q = 0.f;
  for (int p = tid; p < NB * 4; p += 256) {
    int bid = p >> 2, wn = p & 3;
    float2 v = part_t[((long long)bid * 8 + (wm * 4 + wn)) * 64 + local];
    s += v.x; q += v.y;
  }
  rs[tid] = s; rq[tid] = q;
  __syncthreads();
  for (int st = 128; st > 0; st >>= 1) {
    if (tid < st) { rs[tid] += rs[tid + st]; rq[tid] += rq[tid + st]; }
    __syncthreads();
  }
  if (tid == 0) {
    const float n = (float)NPC;
    float m = rs[0] / n, var = rq[0] / n - m * m;
    float sc = g_t[c] * rsqrtf(var + 1e-5f);
    scales[512 + c] = sc;
    scales[640 + c] = be_t[c] - m * sc;
  }
}

// ---------------------------------------------------------------------------
// kH: out = relu(cvb*sc_t+sh_t + resb*sc_r+sh_r). Plane-based (r9-proven):
// grid 4096, us4 bf16 loads + float4 stores, all contiguous per plane.
// ---------------------------------------------------------------------------
__global__ __launch_bounds__(256) void kH(
    const unsigned short* __restrict__ cvb, const unsigned short* __restrict__ resb,
    const float* __restrict__ scales, float* __restrict__ out)
{
  const int plane = blockIdx.x;          // b*128 + c
  const int c = plane & 127;
  const float sct = scales[512 + c], sht = scales[640 + c];
  const float scr = scales[c],       shr = scales[128 + c];
  const us4* cp = (const us4*)&cvb[(long long)plane * TV];
  const us4* rp = (const us4*)&resb[(long long)plane * TV];
  float* op = &out[(long long)plane * TV];
  for (int u = threadIdx.x; u < 1875; u += 256) {
    us4 o4 = cp[u], r4 = rp[u];
    float4 y;
    y.x = fmaxf(bf2f(o4[0]) * sct + sht + bf2f(r4[0]) * scr + shr, 0.f);
    y.y = fmaxf(bf2f(o4[1]) * sct + sht + bf2f(r4[1]) * scr + shr, 0.f);
    y.z = fmaxf(bf2f(o4[2]) * sct + sht + bf2f(r4[2]) * scr + shr, 0.f);
    y.w = fmaxf(bf2f(o4[3]) * sct + sht + bf2f(r4[3]) * scr + shr, 0.f);
    *(float4*)&op[u * 4] = y;
  }
}

// ---------------------------------------------------------------------------
extern "C" void kernel_launch(void* const* d_in, const int* in_sizes, int n_in,
                              void* d_out, int out_size, void* d_ws, size_t ws_size,
                              hipStream_t stream) {
  const float* x     = (const float*)d_in[0];
  const float* A_hat = (const float*)d_in[1];
  const float* w_sp  = (const float*)d_in[2];
  const float* g_sp  = (const float*)d_in[4];
  const float* be_sp = (const float*)d_in[5];
  const float* w_t   = (const float*)d_in[6];
  const float* g_t   = (const float*)d_in[8];
  const float* be_t  = (const float*)d_in[9];
  const float* w_r   = (const float*)d_in[10];
  const float* g_r   = (const float*)d_in[12];
  const float* be_r  = (const float*)d_in[13];
  float* out = (float*)d_out;

  // workspace carving (shorts)
  unsigned short* base_us = (unsigned short*)d_ws;
  unsigned short* resb = base_us;                          // TOTAL ([b][c][pos])
  unsigned short* h    = base_us + (size_t)TOTAL;          // TOTAL ([b][pos][c])
  unsigned short* cvb  = base_us + (size_t)(2 * TOTAL);    // TOTAL ([b][c][pos])
  unsigned short* wb2  = base_us + (size_t)(3 * TOTAL);    // 147456
  unsigned short* wrs2 = wb2 + 147456;                     // 16384
  unsigned short* bdt  = wrs2 + 16384;                     // 14336
  float2* part_rs = (float2*)(bdt + 14336);                // 2400*4*64
  float2* part_t  = part_rs + 2400 * 4 * 64;               // 960*8*64
  float*  scales  = (float*)(part_t + 960 * 8 * 64);       // 768 floats

  // all prep in one launch
  kPrep<<<696, 256, 0, stream>>>(w_t, w_r, w_sp, A_hat, wb2, wrs2, bdt);
  // spatial front-end (stats fused)
  kA6<<<dim3(75, 32), 256, 0, stream>>>(x, bdt, wrs2, resb, h, part_rs);
  kC2v2<<<256, 256, 0, stream>>>(part_rs, g_r, be_r, g_sp, be_sp, scales);
  // temporal conv (NP=256, fused BN_s+ReLU staging, stats fused)
  kE7c<<<dim3(30, 32), 512, 0, stream>>>(h, wb2, scales, cvb, part_t);
  kG2<<<128, 256, 0, stream>>>(part_t, g_t, be_t, scales);
  // fused epilogue (plane-based, r9-proven)
  kH<<<4096, 256, 0, stream>>>(cvb, resb, scales, out);
}